// Round 9
// baseline (277.496 us; speedup 1.0000x reference)
//
#include <hip/hip_runtime.h>
#include <math.h>

#define EPSF 1e-5f
#define NNC 46656

typedef __attribute__((ext_vector_type(4))) float  f32x4;
typedef __attribute__((ext_vector_type(8))) short  short8;
typedef __attribute__((ext_vector_type(8))) unsigned short ushort8;
typedef __attribute__((ext_vector_type(4))) unsigned int uint4v;

__device__ __forceinline__ float bf2f(unsigned short u) {
    unsigned int x = ((unsigned int)u) << 16;
    return __builtin_bit_cast(float, x);
}
__device__ __forceinline__ unsigned short f2bf(float f) {
    unsigned int x = __builtin_bit_cast(unsigned int, f);
    unsigned int r = (x + 0x7fffu + ((x >> 16) & 1u)) >> 16;
    return (unsigned short)r;
}

// packed: relu(bf16x2(H) + bf16x2(S)) -> bf16x2 (truncation pack via v_perm)
__device__ __forceinline__ short8 packrelu8(ushort8 H8, ushort8 S8) {
    uint4v H = __builtin_bit_cast(uint4v, H8);
    uint4v S = __builtin_bit_cast(uint4v, S8);
    uint4v O;
#pragma unroll
    for (int d = 0; d < 4; ++d) {
        float hlo = __builtin_bit_cast(float, H[d] << 16);
        float hhi = __builtin_bit_cast(float, H[d] & 0xffff0000u);
        float slo = __builtin_bit_cast(float, S[d] << 16);
        float shi = __builtin_bit_cast(float, S[d] & 0xffff0000u);
        unsigned int rlo = __builtin_bit_cast(unsigned int, fmaxf(hlo + slo, 0.f));
        unsigned int rhi = __builtin_bit_cast(unsigned int, fmaxf(hhi + shi, 0.f));
        O[d] = __builtin_amdgcn_perm(rhi, rlo, 0x07060302u);
    }
    return __builtin_bit_cast(short8, O);
}

// ---- workspace layout (float offsets) ----
#define WS_SH    37888u      // Sh bf16 [216][1024] -> 110592 f
#define WS_S3    148480u     // S3 bf16 [216][1024] -> 110592 f
#define WS_W2BF  259072u     // W2 bf16 [256][1024] -> 131072 f
#define WS_C2    390144u     // [256] f32
#define WS_W3BF  390400u     // W3 bf16 [784][256] -> 100352 f
#define WS_C3    490752u     // [16] f32
#define WS_XBF   490768u     // X bf16 [64][160] -> 5120 f
#define WS_SX2   495888u     // [64] f32
#define WS_E1T   495952u     // e1n^T [256 o][64 b] f32 -> 16384 f
#define WS_E2T   512336u     // e2n^T [1024 j][64 b] f32 -> 65536 f
#define WS_FLAG  577872u     // int flags[4]: [0]=prep(337) [1]=conv(64) [2]=fc1(256)

#define OBS_SIZE (64*NNC)
#define DIST_OFF OBS_SIZE
#define LOSS_OFF (OBS_SIZE + 64*36)

// Single fused kernel, 53248 B dyn LDS -> 3 blocks/CU.
// Grid 1387: [0,337) table prep -> flags[0] | [337,401) conv -> flags[1] |
// [401,657) fc1 (spin conv) -> flags[2] | 657 logits (spin fc1) |
// [658,1387) decoder (spin prep). Producers (0..400) have NO dependencies ->
// deadlock-free at any occupancy given ascending dispatch (same assumption the
// previously-passing fc1->logits spin already made).
#define LDS_BYTES 53248

__launch_bounds__(256, 3)
__global__ void dvae_all(const float* __restrict__ x,
                         const float* __restrict__ conv_w, const float* __restrict__ conv_b,
                         const float* __restrict__ ebn2_g, const float* __restrict__ ebn2_b,
                         const float* __restrict__ embeds,
                         const float* __restrict__ dfc1_w, const float* __restrict__ dfc1_b,
                         const float* __restrict__ dbn1_g, const float* __restrict__ dbn1_b,
                         const float* __restrict__ dbn1_rm, const float* __restrict__ dbn1_rv,
                         const float* __restrict__ dfc2_w, const float* __restrict__ dfc2_b,
                         const float* __restrict__ dbn2_g, const float* __restrict__ dbn2_b,
                         const float* __restrict__ dbn2_rm, const float* __restrict__ dbn2_rv,
                         const float* __restrict__ dct1_w, const float* __restrict__ dct1_b,
                         const float* __restrict__ dbn3_g, const float* __restrict__ dbn3_b,
                         const float* __restrict__ dbn3_rm, const float* __restrict__ dbn3_rv,
                         const float* __restrict__ dct2_w, const float* __restrict__ dct2_b,
                         const float* __restrict__ fc1_w, const float* __restrict__ fc1_b,
                         const float* __restrict__ ebn1_g, const float* __restrict__ ebn1_b,
                         const float* __restrict__ fc2_w, const float* __restrict__ fc2_b,
                         float* ws, float* out) {
    extern __shared__ char sm[];
    float* sbuf = (float*)sm;
    int bx = blockIdx.x, tid = threadIdx.x;
    int* flags = (int*)(ws + WS_FLAG);

    if (bx < 64) {                       // ---- P' (LDS) -> Sh/S3 slices directly ----
        float* wtile = sbuf;             // [16][193] = 3088
        float* semb  = sbuf + 3088;      // [1152]
        float* Pt    = sbuf + 4240;      // [36][20] = 720
        float* c1s   = sbuf + 4960;      // [16]
        int j0 = bx * 16;
        for (int e = tid; e < 16 * 192; e += 256)
            wtile[(e / 192) * 193 + (e % 192)] = dfc1_w[j0 * 192 + e];
        for (int e = tid; e < 1152; e += 256) semb[e] = embeds[e];
        __syncthreads();
        for (int e = tid; e < 576; e += 256) {
            int vk = e >> 4, jL = e & 15;
            int v = vk / 6;
            int j = j0 + jL;
            const float* wrow = &wtile[jL * 193 + v * 32];
            const float* ep = &semb[vk * 32];
            float dot = 0.f;
#pragma unroll
            for (int d = 0; d < 32; ++d) dot += wrow[d] * ep[d];
            float s1 = dbn1_g[j] * rsqrtf(dbn1_rv[j] + EPSF);
            Pt[vk * 20 + jL] = s1 * dot;
        }
        if (tid < 16) {
            int j = j0 + tid;
            float s = dbn1_g[j] * rsqrtf(dbn1_rv[j] + EPSF);
            c1s[tid] = s * dfc1_b[j] + dbn1_b[j] - dbn1_rm[j] * s;
        }
        __syncthreads();
        unsigned short* Sh = (unsigned short*)(ws + WS_SH);
        unsigned short* S3 = (unsigned short*)(ws + WS_S3);
        for (int e = tid; e < 216 * 16; e += 256) {
            int gh = e >> 4, jL = e & 15;
            int d0 = gh / 36, d1 = (gh / 6) % 6, d2 = gh % 6;
            float vh = c1s[jL] + Pt[d0 * 20 + jL] + Pt[(6 + d1) * 20 + jL] + Pt[(12 + d2) * 20 + jL];
            float vs = Pt[(18 + d0) * 20 + jL] + Pt[(24 + d1) * 20 + jL] + Pt[(30 + d2) * 20 + jL];
            Sh[gh * 1024 + j0 + jL] = f2bf(vh);
            S3[gh * 1024 + j0 + jL] = f2bf(vs);
        }
        __syncthreads();
        if (tid == 0) { __threadfence(); atomicAdd(&flags[0], 1); }
        return;
    }

    if (bx < 320) {                      // ---- W2 bf16 + c2 ----
        int t = (bx - 64) * 256 + tid;
        int i = t >> 8, kq = (t & 255) * 4;
        float s2 = dbn2_g[i] * rsqrtf(dbn2_rv[i] + EPSF);
        float4 w = *(const float4*)(dfc2_w + i * 1024 + kq);
        unsigned short* dst = (unsigned short*)(ws + WS_W2BF) + i * 1024 + kq;
        dst[0] = f2bf(s2 * w.x); dst[1] = f2bf(s2 * w.y);
        dst[2] = f2bf(s2 * w.z); dst[3] = f2bf(s2 * w.w);
        if (kq == 0) ws[WS_C2 + i] = s2 * dfc2_b[i] + dbn2_b[i] - dbn2_rm[i] * s2;
        __syncthreads();
        if (tid == 0) { __threadfence(); atomicAdd(&flags[0], 1); }
        return;
    }

    if (bx < 336) {                      // ---- W3 bf16 + c3 (LDS transpose) ----
        int blk = bx - 320;
        for (int e = tid; e < 12544; e += 256) sbuf[e] = dct1_w[blk * 12544 + e];
        __syncthreads();
        unsigned short* W3 = (unsigned short*)(ws + WS_W3BF);
        for (int e = tid; e < 1568; e += 256) {
            int up = e >> 1, k8 = (e & 1) * 8;
            int o = up & 15, hw = up >> 4;
            float s3 = dbn3_g[o] * rsqrtf(dbn3_rv[o] + EPSF);
            ushort8 ov;
#pragma unroll
            for (int t2 = 0; t2 < 8; ++t2)
                ov[t2] = f2bf(s3 * sbuf[(k8 + t2) * 784 + o * 49 + hw]);
            *(ushort8*)(W3 + up * 256 + blk * 16 + k8) = ov;
        }
        if (blk == 0 && tid < 16) {
            float s = dbn3_g[tid] * rsqrtf(dbn3_rv[tid] + EPSF);
            ws[WS_C3 + tid] = s * dct1_b[tid] + dbn3_b[tid] - dbn3_rm[tid] * s;
        }
        __syncthreads();
        if (tid == 0) { __threadfence(); atomicAdd(&flags[0], 1); }
        return;
    }

    if (bx == 336) {                     // ---- X bf16 + sum(x^2) ----
        unsigned short* Xb = (unsigned short*)(ws + WS_XBF);
        if (tid < 64) {
            const float* xp = x + tid * 147;
            float s = 0.f;
            for (int qq = 0; qq < 147; ++qq) { float v = xp[qq]; s += v * v; }
            ws[WS_SX2 + tid] = s;
        }
        for (int e = tid; e < 64 * 160; e += 256) {
            int b = e / 160, col = e % 160;
            float v = 0.f;
            if (col < 147) { int hw = col / 3, c = col % 3; v = x[b * 147 + c * 49 + hw]; }
            Xb[e] = f2bf(v);
        }
        __syncthreads();
        if (tid == 0) { __threadfence(); atomicAdd(&flags[0], 1); }
        return;
    }

    if (bx < 401) {                      // ---- conv + BN-train (x staged in LDS) ----
        int blk = bx - 337;
        for (int e = tid; e < 9408; e += 256) sbuf[e] = x[e];
        __syncthreads();
        int b = tid & 63;
        int oL = __builtin_amdgcn_readfirstlane(tid >> 6);
        int o = blk * 4 + oL;
        const float* wp = conv_w + o * 147;
        float acc = conv_b[o];
#pragma unroll 7
        for (int qq = 0; qq < 147; ++qq) acc += sbuf[b * 147 + qq] * wp[qq];
        float m = acc;
#pragma unroll
        for (int s = 1; s < 64; s <<= 1) m += __shfl_xor(m, s);
        m *= (1.f / 64.f);
        float d = acc - m;
        float var = d * d;
#pragma unroll
        for (int s = 1; s < 64; s <<= 1) var += __shfl_xor(var, s);
        var *= (1.f / 64.f);
        float y = ebn2_g[o] * d * rsqrtf(var + EPSF) + ebn2_b[o];
        ws[WS_E1T + o * 64 + b] = fmaxf(y, 0.f);
        __syncthreads();
        if (tid == 0) { __threadfence(); atomicAdd(&flags[1], 1); }
        return;
    }

    if (bx < 657) {                      // ---- fc1 + BN-train -> e2T (spin on conv) ----
        if (tid == 0) {
            while (atomicAdd(&flags[1], 0) < 64) __builtin_amdgcn_s_sleep(8);
        }
        __syncthreads();
        const float* e1T = ws + WS_E1T;
        float* e2T = ws + WS_E2T;
        int blk = bx - 401;
        int b = tid & 63;
        int jL = __builtin_amdgcn_readfirstlane(tid >> 6);
        int j = blk * 4 + jL;
        const float* wp = fc1_w + j * 256;
        float acc = fc1_b[j];
#pragma unroll 8
        for (int o = 0; o < 256; ++o) acc += e1T[o * 64 + b] * wp[o];
        float m = acc;
#pragma unroll
        for (int s = 1; s < 64; s <<= 1) m += __shfl_xor(m, s);
        m *= (1.f / 64.f);
        float d = acc - m;
        float var = d * d;
#pragma unroll
        for (int s = 1; s < 64; s <<= 1) var += __shfl_xor(var, s);
        var *= (1.f / 64.f);
        float y = ebn1_g[j] * d * rsqrtf(var + EPSF) + ebn1_b[j];
        e2T[j * 64 + b] = fmaxf(y, 0.f);
        __syncthreads();
        if (tid == 0) { __threadfence(); atomicAdd(&flags[2], 1); }
        return;
    }

    if (bx == 657) {                     // ---- logits (spin on fc1) ----
        if (tid == 0) {
            while (atomicAdd(&flags[2], 0) < 256) __builtin_amdgcn_s_sleep(8);
        }
        __syncthreads();
        const float* e2T = ws + WS_E2T;
        float* wch = (float*)sm;              // [36][128]
        float* ech = (float*)(sm + 18432);    // [128][64]
        float* LG  = (float*)sm;              // [64][36] (aliases wch after barrier)
        int b = tid & 63;
        int wvU = __builtin_amdgcn_readfirstlane(tid >> 6);
        float accv[9];
#pragma unroll
        for (int it = 0; it < 9; ++it) accv[it] = 0.f;
        for (int ch = 0; ch < 8; ++ch) {
            __syncthreads();
            for (int e = tid; e < 36 * 128; e += 256)
                wch[e] = fc2_w[(e >> 7) * 1024 + ch * 128 + (e & 127)];
            for (int e = tid; e < 128 * 64; e += 256)
                ech[e] = e2T[(ch * 128 + (e >> 6)) * 64 + (e & 63)];
            __syncthreads();
            for (int jl = 0; jl < 128; ++jl) {
                float ev = ech[jl * 64 + b];
#pragma unroll
                for (int it = 0; it < 9; ++it)
                    accv[it] += ev * wch[(wvU + it * 4) * 128 + jl];
            }
        }
        __syncthreads();   // staging buffers dead; LG may alias them now
#pragma unroll
        for (int it = 0; it < 9; ++it) {
            int o = wvU + it * 4;
            LG[b * 36 + o] = accv[it] + fc2_b[o];
        }
        __syncthreads();
        if (tid < 64) {
            float loss = 0.f;
#pragma unroll
            for (int v = 0; v < 6; ++v) {
                float mx = -1e30f;
#pragma unroll
                for (int k = 0; k < 6; ++k) mx = fmaxf(mx, LG[tid * 36 + v * 6 + k]);
                float s = 0.f, ex[6];
#pragma unroll
                for (int k = 0; k < 6; ++k) { ex[k] = expf(LG[tid * 36 + v * 6 + k] - mx); s += ex[k]; }
                float inv = 1.f / s;
#pragma unroll
                for (int k = 0; k < 6; ++k) {
                    float dd = ex[k] * inv;
                    out[DIST_OFF + tid * 36 + v * 6 + k] = dd;
                    loss += dd * logf(dd + 1e-10f);
                }
            }
            out[LOSS_OFF + tid] = 0.1f * loss;
        }
        return;
    }

    // ---- decoder (spin on table prep; R2-best body verbatim) ----
    if (tid == 0) {
        while (atomicAdd(&flags[0], 0) < 337) __builtin_amdgcn_s_sleep(8);
    }
    __syncthreads();

    const unsigned short* Sh  = (const unsigned short*)(ws + WS_SH);
    const unsigned short* S3g = (const unsigned short*)(ws + WS_S3);
    const unsigned short* W2  = (const unsigned short*)(ws + WS_W2BF);
    const float* c2g = ws + WS_C2;
    const unsigned short* W3  = (const unsigned short*)(ws + WS_W3BF);
    const float* c3g = ws + WS_C3;
    const unsigned short* Xg  = (const unsigned short*)(ws + WS_XBF);
    const float* sx2g = ws + WS_SX2;

    int wv = tid >> 6, lane = tid & 63, l15 = lane & 15, q = lane >> 4;
    int db = bx - 658;
    int g0 = (db / 27) * 8, r0 = (db % 27) * 8;   // 2-D tile: 8 gh-rows x 8 r216-rows
    unsigned short* emL = (unsigned short*)sm;            // [64][160] bf16 = 20480
    unsigned short* h2L = (unsigned short*)(sm + 20480);  // [32 kb][64 m][8] = 32768
    float* sE2p = (float*)(sm + 20480);                   // aliases h2L (after barrier)
    float* sE2f = (float*)(sm + 21504);
    char* Ast = sm;   // GEMM1 A staging, 2x16KB dbuf (aliases emL + h2L head; dead before h2L)

    f32x4 acc[4][4];
#pragma unroll
    for (int a = 0; a < 4; ++a)
#pragma unroll
        for (int b = 0; b < 4; ++b) acc[a][b] = (f32x4){0.f, 0.f, 0.f, 0.f};

    // cooperative staged GEMM1: local row rho = lane (gh = g0 + rho/8, r216 = r0 + rho%8)
    int gh_t = g0 + (lane >> 3);
    int r_t  = r0 + (lane & 7);
    const unsigned short* shp = Sh  + gh_t * 1024 + wv * 32;
    const unsigned short* s3p = S3g + r_t  * 1024 + wv * 32;
    const unsigned short* bbase = W2 + (wv * 64 + l15) * 1024 + q * 8;
    int Xw = (lane & 7) << 4;   // write-side XOR swizzle
    int Xr = (l15 & 7) << 4;    // read-side XOR swizzle

    ushort8 rsh[4], rs3[4];
#pragma unroll
    for (int i = 0; i < 4; ++i) {
        rsh[i] = *(const ushort8*)(shp + i * 8);
        rs3[i] = *(const ushort8*)(s3p + i * 8);
    }
    short8 bpre[4];
#pragma unroll
    for (int j = 0; j < 4; ++j) bpre[j] = *(const short8*)(bbase + j * 16384);
#pragma unroll
    for (int i = 0; i < 4; ++i)
        *(short8*)(Ast + lane * 256 + ((wv * 64 + i * 16) ^ Xw)) = packrelu8(rsh[i], rs3[i]);
    __syncthreads();

    for (int c = 0; c < 8; ++c) {
        int cb = (c & 1) << 14;
        if (c < 7) {   // issue next-chunk table loads early
            const unsigned short* p1 = shp + (c + 1) * 128;
            const unsigned short* p3 = s3p + (c + 1) * 128;
#pragma unroll
            for (int i = 0; i < 4; ++i) {
                rsh[i] = *(const ushort8*)(p1 + i * 8);
                rs3[i] = *(const ushort8*)(p3 + i * 8);
            }
        }
#pragma unroll
        for (int ss = 0; ss < 4; ++ss) {
            int s = c * 4 + ss;
            short8 af[4];
#pragma unroll
            for (int mt = 0; mt < 4; ++mt)
                af[mt] = *(const short8*)(Ast + cb + (mt * 16 + l15) * 256 + ((ss * 64 + q * 16) ^ Xr));
            short8 bcur[4];
#pragma unroll
            for (int j = 0; j < 4; ++j) bcur[j] = bpre[j];
            if (s < 31) {
#pragma unroll
                for (int j = 0; j < 4; ++j) bpre[j] = *(const short8*)(bbase + j * 16384 + (s + 1) * 32);
            }
#pragma unroll
            for (int mt = 0; mt < 4; ++mt)
#pragma unroll
                for (int j = 0; j < 4; ++j)
                    acc[mt][j] = __builtin_amdgcn_mfma_f32_16x16x32_bf16(af[mt], bcur[j], acc[mt][j], 0, 0, 0);
        }
        if (c < 7) {
            int nb = ((c + 1) & 1) << 14;
#pragma unroll
            for (int i = 0; i < 4; ++i)
                *(short8*)(Ast + nb + lane * 256 + ((wv * 64 + i * 16) ^ Xw)) = packrelu8(rsh[i], rs3[i]);
        }
        __syncthreads();
    }

#pragma unroll
    for (int j = 0; j < 4; ++j) {
        int i = wv * 64 + j * 16 + l15;
        float cc = c2g[i];
#pragma unroll
        for (int mt = 0; mt < 4; ++mt)
#pragma unroll
            for (int r = 0; r < 4; ++r) {
                int m = mt * 16 + q * 4 + r;
                h2L[((i >> 3) * 64 + m) * 8 + (i & 7)] = f2bf(fmaxf(acc[mt][j][r] + cc, 0.f));
            }
    }
    __syncthreads();

    // ---- GEMM2 (operand-swapped: D[o = q*4+r][m = l15]) + in-register dct2 contraction ----
    float c3q[4], dwq0[4], dwq1[4], dwq2[4];
#pragma unroll
    for (int r = 0; r < 4; ++r) {
        int o = q * 4 + r;
        c3q[r]  = c3g[o];
        dwq0[r] = dct2_w[o * 3 + 0];
        dwq1[r] = dct2_w[o * 3 + 1];
        dwq2[r] = dct2_w[o * 3 + 2];
    }
    float db0 = dct2_b[0], db1 = dct2_b[1], db2 = dct2_b[2];
    float sE2acc[4] = {0.f, 0.f, 0.f, 0.f};

    for (int c = wv; c < 13; c += 4) {
        int hw0 = c * 4;
        f32x4 a2[4][4];
#pragma unroll
        for (int a = 0; a < 4; ++a)
#pragma unroll
            for (int b = 0; b < 4; ++b) a2[a][b] = (f32x4){0.f, 0.f, 0.f, 0.f};
        const unsigned short* b3[4];
#pragma unroll
        for (int j = 0; j < 4; ++j) {
            int hw = hw0 + j; if (hw > 48) hw = 48;
            b3[j] = W3 + (hw * 16 + l15) * 256 + q * 8;
        }
        short8 bpre2[4];
#pragma unroll
        for (int j = 0; j < 4; ++j) bpre2[j] = *(const short8*)(b3[j]);
#pragma unroll
        for (int s = 0; s < 8; ++s) {
            short8 bcur[4];
#pragma unroll
            for (int j = 0; j < 4; ++j) bcur[j] = bpre2[j];
            if (s < 7) {
#pragma unroll
                for (int j = 0; j < 4; ++j) bpre2[j] = *(const short8*)(b3[j] + (s + 1) * 32);
            }
            short8 af[4];
#pragma unroll
            for (int mt = 0; mt < 4; ++mt)
                af[mt] = *(const short8*)(h2L + ((s * 4 + q) * 64 + mt * 16 + l15) * 8);
            // swapped: A = W3 fragment (rows=o), B = H2 fragment (cols=m)
#pragma unroll
            for (int mt = 0; mt < 4; ++mt)
#pragma unroll
                for (int j = 0; j < 4; ++j)
                    a2[mt][j] = __builtin_amdgcn_mfma_f32_16x16x32_bf16(bcur[j], af[mt], a2[mt][j], 0, 0, 0);
        }
#pragma unroll
        for (int j = 0; j < 4; ++j) {
            int hw = hw0 + j;
            if (hw <= 48) {
#pragma unroll
                for (int mt = 0; mt < 4; ++mt) {
                    // lane holds h3[o=q*4+r][m=mt*16+l15], r=0..3
                    float p0 = 0.f, p1 = 0.f, p2 = 0.f;
#pragma unroll
                    for (int r = 0; r < 4; ++r) {
                        float h = fmaxf(a2[mt][j][r] + c3q[r], 0.f);
                        p0 += h * dwq0[r]; p1 += h * dwq1[r]; p2 += h * dwq2[r];
                    }
                    // reduce over q-groups (lanes ±16, ±32): all lanes get full sums
                    p0 += __shfl_xor(p0, 16); p0 += __shfl_xor(p0, 32);
                    p1 += __shfl_xor(p1, 16); p1 += __shfl_xor(p1, 32);
                    p2 += __shfl_xor(p2, 16); p2 += __shfl_xor(p2, 32);
                    unsigned short u0 = f2bf(p0 + db0), u1 = f2bf(p1 + db1), u2 = f2bf(p2 + db2);
                    float f0 = bf2f(u0), f1 = bf2f(u1), f2v = bf2f(u2);
                    if (q == 0) {
                        sE2acc[mt] += f0 * f0 + f1 * f1 + f2v * f2v;
                        unsigned short* er = emL + (mt * 16 + l15) * 160 + hw * 3;
                        er[0] = u0; er[1] = u1; er[2] = u2;
                    }
                }
            }
        }
    }
    __syncthreads();   // all h2L reads complete; sE2p/sE2f may alias it now
    if (q == 0) {
#pragma unroll
        for (int mt = 0; mt < 4; ++mt) sE2p[wv * 64 + mt * 16 + l15] = sE2acc[mt];
    }
    for (int e = tid; e < 64 * 13; e += 256) emL[(e / 13) * 160 + 147 + (e % 13)] = 0;
    __syncthreads();
    if (tid < 64) sE2f[tid] = sE2p[tid] + sE2p[64 + tid] + sE2p[128 + tid] + sE2p[192 + tid];
    __syncthreads();

    f32x4 aO[4];
#pragma unroll
    for (int j = 0; j < 4; ++j) aO[j] = (f32x4){0.f, 0.f, 0.f, 0.f};
    const unsigned short* xrow = Xg + (wv * 16 + l15) * 160 + q * 8;
#pragma unroll
    for (int s = 0; s < 5; ++s) {
        short8 af = *(const short8*)(xrow + s * 32);
#pragma unroll
        for (int j = 0; j < 4; ++j) {
            short8 bfv = *(const short8*)(emL + (j * 16 + l15) * 160 + s * 32 + q * 8);
            aO[j] = __builtin_amdgcn_mfma_f32_16x16x32_bf16(af, bfv, aO[j], 0, 0, 0);
        }
    }
    int b0 = wv * 16 + q * 4;
    float sxv[4];
#pragma unroll
    for (int r = 0; r < 4; ++r) sxv[r] = sx2g[b0 + r];
#pragma unroll
    for (int j = 0; j < 4; ++j) {
        int rloc = j * 16 + l15;
        int n = (g0 + (rloc >> 3)) * 216 + r0 + (rloc & 7);   // 2-D tile -> global code index
        float he = 0.5f * sE2f[rloc];
#pragma unroll
        for (int r = 0; r < 4; ++r)
            out[(size_t)(b0 + r) * NNC + n] = aO[j][r] - he - 0.5f * sxv[r];
    }
}

// ============================ launcher ============================

extern "C" void kernel_launch(void* const* d_in, const int* in_sizes, int n_in,
                              void* d_out, int out_size, void* d_ws, size_t ws_size,
                              hipStream_t stream) {
    const float* x       = (const float*)d_in[0];
    const float* conv_w  = (const float*)d_in[1];
    const float* conv_b  = (const float*)d_in[2];
    const float* ebn2_g  = (const float*)d_in[3];
    const float* ebn2_b  = (const float*)d_in[4];
    const float* fc1_w   = (const float*)d_in[5];
    const float* fc1_b   = (const float*)d_in[6];
    const float* ebn1_g  = (const float*)d_in[7];
    const float* ebn1_b  = (const float*)d_in[8];
    const float* fc2_w   = (const float*)d_in[9];
    const float* fc2_b   = (const float*)d_in[10];
    const float* embeds  = (const float*)d_in[11];
    const float* dfc1_w  = (const float*)d_in[12];
    const float* dfc1_b  = (const float*)d_in[13];
    const float* dbn1_g  = (const float*)d_in[14];
    const float* dbn1_b  = (const float*)d_in[15];
    const float* dbn1_rm = (const float*)d_in[16];
    const float* dbn1_rv = (const float*)d_in[17];
    const float* dfc2_w  = (const float*)d_in[18];
    const float* dfc2_b  = (const float*)d_in[19];
    const float* dbn2_g  = (const float*)d_in[20];
    const float* dbn2_b  = (const float*)d_in[21];
    const float* dbn2_rm = (const float*)d_in[22];
    const float* dbn2_rv = (const float*)d_in[23];
    const float* dct1_w  = (const float*)d_in[24];
    const float* dct1_b  = (const float*)d_in[25];
    const float* dbn3_g  = (const float*)d_in[26];
    const float* dbn3_b  = (const float*)d_in[27];
    const float* dbn3_rm = (const float*)d_in[28];
    const float* dbn3_rv = (const float*)d_in[29];
    const float* dct2_w  = (const float*)d_in[30];
    const float* dct2_b  = (const float*)d_in[31];

    float* ws  = (float*)d_ws;
    float* out = (float*)d_out;

    hipMemsetAsync((void*)(ws + WS_FLAG), 0, 16, stream);   // zero flags[0..3]

    hipFuncSetAttribute(reinterpret_cast<const void*>(dvae_all),
                        hipFuncAttributeMaxDynamicSharedMemorySize, LDS_BYTES);
    dvae_all<<<1387, 256, LDS_BYTES, stream>>>(
        x, conv_w, conv_b, ebn2_g, ebn2_b, embeds,
        dfc1_w, dfc1_b, dbn1_g, dbn1_b, dbn1_rm, dbn1_rv,
        dfc2_w, dfc2_b, dbn2_g, dbn2_b, dbn2_rm, dbn2_rv,
        dct1_w, dct1_b, dbn3_g, dbn3_b, dbn3_rm, dbn3_rv,
        dct2_w, dct2_b, fc1_w, fc1_b, ebn1_g, ebn1_b, fc2_w, fc2_b,
        ws, out);
}

// Round 10
// 255.045 us; speedup vs baseline: 1.0880x; 1.0880x over previous
//
#include <hip/hip_runtime.h>
#include <math.h>

#define EPSF 1e-5f
#define NNC 46656

typedef __attribute__((ext_vector_type(4))) float  f32x4;
typedef __attribute__((ext_vector_type(8))) short  short8;
typedef __attribute__((ext_vector_type(8))) unsigned short ushort8;
typedef __attribute__((ext_vector_type(4))) unsigned int uint4v;

// barrier with LDS-only drain: keeps register-destined global prefetch in flight.
// Correct where all cross-thread traffic is LDS (lgkm): pack writes + Ast reads
// are lgkm-drained; B/table global loads are register-destined (no visibility need).
#define BAR_LGKM() asm volatile("s_waitcnt lgkmcnt(0)\n\ts_barrier" ::: "memory")

__device__ __forceinline__ float bf2f(unsigned short u) {
    unsigned int x = ((unsigned int)u) << 16;
    return __builtin_bit_cast(float, x);
}
__device__ __forceinline__ unsigned short f2bf(float f) {
    unsigned int x = __builtin_bit_cast(unsigned int, f);
    unsigned int r = (x + 0x7fffu + ((x >> 16) & 1u)) >> 16;
    return (unsigned short)r;
}

// packed: relu(bf16x2(H) + bf16x2(S)) -> bf16x2 (truncation pack via v_perm)
__device__ __forceinline__ short8 packrelu8(ushort8 H8, ushort8 S8) {
    uint4v H = __builtin_bit_cast(uint4v, H8);
    uint4v S = __builtin_bit_cast(uint4v, S8);
    uint4v O;
#pragma unroll
    for (int d = 0; d < 4; ++d) {
        float hlo = __builtin_bit_cast(float, H[d] << 16);
        float hhi = __builtin_bit_cast(float, H[d] & 0xffff0000u);
        float slo = __builtin_bit_cast(float, S[d] << 16);
        float shi = __builtin_bit_cast(float, S[d] & 0xffff0000u);
        unsigned int rlo = __builtin_bit_cast(unsigned int, fmaxf(hlo + slo, 0.f));
        unsigned int rhi = __builtin_bit_cast(unsigned int, fmaxf(hhi + shi, 0.f));
        O[d] = __builtin_amdgcn_perm(rhi, rlo, 0x07060302u);
    }
    return __builtin_bit_cast(short8, O);
}

// ---- workspace layout (float offsets) ----
#define WS_SH    37888u      // Sh bf16 [216][1024] -> 110592 f
#define WS_S3    148480u     // S3 bf16 [216][1024] -> 110592 f
#define WS_W2BF  259072u     // W2 bf16 [256][1024] -> 131072 f
#define WS_C2    390144u     // [256] f32
#define WS_W3BF  390400u     // W3 bf16 [784][256] -> 100352 f
#define WS_C3    490752u     // [16] f32
#define WS_XBF   490768u     // X bf16 [64][160] -> 5120 f
#define WS_SX2   495888u     // [64] f32
#define WS_E1T   495952u     // e1n^T [256 o][64 b] f32 -> 16384 f
#define WS_E2T   512336u     // e2n^T [1024 j][64 b] f32 -> 65536 f
#define WS_FLAG  577872u     // int completion flag for fc1 blocks

#define OBS_SIZE (64*NNC)
#define DIST_OFF OBS_SIZE
#define LOSS_OFF (OBS_SIZE + 64*36)

// 53248 B -> 3 blocks/CU. Best-measured config (R2): fc1 [0,256) first (stagger),
// logits 256, decoders [257,986). Two-kernel split (fusion costs +20 µs, R9).
#define LDS_BYTES 53248

// ============================ K1: all prep + tables + conv/BN ============================
// blocks: [0,64) P'+Sh/S3 tables | [64,320) W2 | [320,336) W3 | 336 X+flag | [337,401) conv+BN

__global__ void dvae_k1(const float* __restrict__ x,
                        const float* __restrict__ conv_w, const float* __restrict__ conv_b,
                        const float* __restrict__ ebn2_g, const float* __restrict__ ebn2_b,
                        const float* __restrict__ embeds, const float* __restrict__ dfc1_w,
                        const float* __restrict__ dfc1_b,
                        const float* __restrict__ dbn1_g, const float* __restrict__ dbn1_b,
                        const float* __restrict__ dbn1_rm, const float* __restrict__ dbn1_rv,
                        const float* __restrict__ dfc2_w, const float* __restrict__ dfc2_b,
                        const float* __restrict__ dbn2_g, const float* __restrict__ dbn2_b,
                        const float* __restrict__ dbn2_rm, const float* __restrict__ dbn2_rv,
                        const float* __restrict__ dct1_w, const float* __restrict__ dct1_b,
                        const float* __restrict__ dbn3_g, const float* __restrict__ dbn3_b,
                        const float* __restrict__ dbn3_rm, const float* __restrict__ dbn3_rv,
                        float* __restrict__ ws) {
    __shared__ float sbuf[12544];
    int bx = blockIdx.x, tid = threadIdx.x;
    if (bx < 64) {                       // ---- P' (LDS) -> Sh/S3 slices directly ----
        float* wtile = sbuf;             // [16][193] = 3088
        float* semb  = sbuf + 3088;      // [1152]
        float* Pt    = sbuf + 4240;      // [36][20] = 720
        float* c1s   = sbuf + 4960;      // [16]
        int j0 = bx * 16;
        for (int e = tid; e < 16 * 192; e += 256)
            wtile[(e / 192) * 193 + (e % 192)] = dfc1_w[j0 * 192 + e];
        for (int e = tid; e < 1152; e += 256) semb[e] = embeds[e];
        __syncthreads();
        for (int e = tid; e < 576; e += 256) {
            int vk = e >> 4, jL = e & 15;
            int v = vk / 6;
            int j = j0 + jL;
            const float* wrow = &wtile[jL * 193 + v * 32];
            const float* ep = &semb[vk * 32];
            float dot = 0.f;
#pragma unroll
            for (int d = 0; d < 32; ++d) dot += wrow[d] * ep[d];
            float s1 = dbn1_g[j] * rsqrtf(dbn1_rv[j] + EPSF);
            Pt[vk * 20 + jL] = s1 * dot;
        }
        if (tid < 16) {
            int j = j0 + tid;
            float s = dbn1_g[j] * rsqrtf(dbn1_rv[j] + EPSF);
            c1s[tid] = s * dfc1_b[j] + dbn1_b[j] - dbn1_rm[j] * s;
        }
        __syncthreads();
        unsigned short* Sh = (unsigned short*)(ws + WS_SH);
        unsigned short* S3 = (unsigned short*)(ws + WS_S3);
        for (int e = tid; e < 216 * 16; e += 256) {
            int gh = e >> 4, jL = e & 15;
            int d0 = gh / 36, d1 = (gh / 6) % 6, d2 = gh % 6;
            float vh = c1s[jL] + Pt[d0 * 20 + jL] + Pt[(6 + d1) * 20 + jL] + Pt[(12 + d2) * 20 + jL];
            float vs = Pt[(18 + d0) * 20 + jL] + Pt[(24 + d1) * 20 + jL] + Pt[(30 + d2) * 20 + jL];
            Sh[gh * 1024 + j0 + jL] = f2bf(vh);
            S3[gh * 1024 + j0 + jL] = f2bf(vs);
        }
    } else if (bx < 320) {               // ---- W2 bf16 + c2 ----
        int t = (bx - 64) * 256 + tid;
        int i = t >> 8, kq = (t & 255) * 4;
        float s2 = dbn2_g[i] * rsqrtf(dbn2_rv[i] + EPSF);
        float4 w = *(const float4*)(dfc2_w + i * 1024 + kq);
        unsigned short* dst = (unsigned short*)(ws + WS_W2BF) + i * 1024 + kq;
        dst[0] = f2bf(s2 * w.x); dst[1] = f2bf(s2 * w.y);
        dst[2] = f2bf(s2 * w.z); dst[3] = f2bf(s2 * w.w);
        if (kq == 0) ws[WS_C2 + i] = s2 * dfc2_b[i] + dbn2_b[i] - dbn2_rm[i] * s2;
    } else if (bx < 336) {               // ---- W3 bf16 + c3 (LDS transpose) ----
        int blk = bx - 320;
        for (int e = tid; e < 12544; e += 256) sbuf[e] = dct1_w[blk * 12544 + e];
        __syncthreads();
        unsigned short* W3 = (unsigned short*)(ws + WS_W3BF);
        for (int e = tid; e < 1568; e += 256) {
            int up = e >> 1, k8 = (e & 1) * 8;
            int o = up & 15, hw = up >> 4;
            float s3 = dbn3_g[o] * rsqrtf(dbn3_rv[o] + EPSF);
            ushort8 ov;
#pragma unroll
            for (int t2 = 0; t2 < 8; ++t2)
                ov[t2] = f2bf(s3 * sbuf[(k8 + t2) * 784 + o * 49 + hw]);
            *(ushort8*)(W3 + up * 256 + blk * 16 + k8) = ov;
        }
        if (blk == 0 && tid < 16) {
            float s = dbn3_g[tid] * rsqrtf(dbn3_rv[tid] + EPSF);
            ws[WS_C3 + tid] = s * dct1_b[tid] + dbn3_b[tid] - dbn3_rm[tid] * s;
        }
    } else if (bx == 336) {              // ---- X bf16 + sum(x^2) + flag zero ----
        unsigned short* Xb = (unsigned short*)(ws + WS_XBF);
        if (tid == 0) *(int*)(ws + WS_FLAG) = 0;
        if (tid < 64) {
            const float* xp = x + tid * 147;
            float s = 0.f;
            for (int qq = 0; qq < 147; ++qq) { float v = xp[qq]; s += v * v; }
            ws[WS_SX2 + tid] = s;
        }
        for (int e = tid; e < 64 * 160; e += 256) {
            int b = e / 160, col = e % 160;
            float v = 0.f;
            if (col < 147) { int hw = col / 3, c = col % 3; v = x[b * 147 + c * 49 + hw]; }
            Xb[e] = f2bf(v);
        }
    } else {                             // ---- conv + BN-train (x staged in LDS) ----
        int blk = bx - 337;
        for (int e = tid; e < 9408; e += 256) sbuf[e] = x[e];
        __syncthreads();
        int b = tid & 63;
        int oL = __builtin_amdgcn_readfirstlane(tid >> 6);
        int o = blk * 4 + oL;
        const float* wp = conv_w + o * 147;
        float acc = conv_b[o];
#pragma unroll 7
        for (int qq = 0; qq < 147; ++qq) acc += sbuf[b * 147 + qq] * wp[qq];
        float m = acc;
#pragma unroll
        for (int s = 1; s < 64; s <<= 1) m += __shfl_xor(m, s);
        m *= (1.f / 64.f);
        float d = acc - m;
        float var = d * d;
#pragma unroll
        for (int s = 1; s < 64; s <<= 1) var += __shfl_xor(var, s);
        var *= (1.f / 64.f);
        float y = ebn2_g[o] * d * rsqrtf(var + EPSF) + ebn2_b[o];
        ws[WS_E1T + o * 64 + b] = fmaxf(y, 0.f);
    }
}

// ============================ K3: fc1 blocks + logits (spin) + decoder ============================
// blocks: [0,256) fc1+BN -> e2T, signal flag | 256 logits (spin on flag) | [257,986) decoder
// decoder = R2-best body (1-deep prefetch) + lgkm-only barriers in the GEMM1 chunk loop

__launch_bounds__(256, 3)
__global__ void dvae_k3(const unsigned short* __restrict__ Sh,
                        const unsigned short* __restrict__ S3g,
                        const unsigned short* __restrict__ W2,
                        const float* __restrict__ c2g,
                        const unsigned short* __restrict__ W3,
                        const float* __restrict__ c3g,
                        const float* __restrict__ d2wg,
                        const float* __restrict__ d2bg,
                        const unsigned short* __restrict__ Xg,
                        const float* __restrict__ sx2g,
                        const float* __restrict__ fc1_w, const float* __restrict__ fc1_b,
                        const float* __restrict__ ebn1_g, const float* __restrict__ ebn1_b,
                        const float* __restrict__ e1T,
                        float* __restrict__ e2T,
                        int* __restrict__ flag,
                        const float* __restrict__ fc2_w,
                        const float* __restrict__ fc2_b,
                        float* __restrict__ out) {
    extern __shared__ char sm[];
    int tid = threadIdx.x;

    if (blockIdx.x < 256) {
        // ---- fc1 + BN-train -> e2T, then signal ----
        int blk = blockIdx.x;
        int b = tid & 63;
        int jL = __builtin_amdgcn_readfirstlane(tid >> 6);
        int j = blk * 4 + jL;
        const float* wp = fc1_w + j * 256;
        float acc = fc1_b[j];
#pragma unroll 8
        for (int o = 0; o < 256; ++o) acc += e1T[o * 64 + b] * wp[o];
        float m = acc;
#pragma unroll
        for (int s = 1; s < 64; s <<= 1) m += __shfl_xor(m, s);
        m *= (1.f / 64.f);
        float d = acc - m;
        float var = d * d;
#pragma unroll
        for (int s = 1; s < 64; s <<= 1) var += __shfl_xor(var, s);
        var *= (1.f / 64.f);
        float y = ebn1_g[j] * d * rsqrtf(var + EPSF) + ebn1_b[j];
        e2T[j * 64 + b] = fmaxf(y, 0.f);
        __syncthreads();
        if (tid == 0) { __threadfence(); atomicAdd(flag, 1); }
        return;
    }

    if (blockIdx.x == 256) {
        // ---- logits: wait for fc1, then LDS-staged GEMM + softmax + entropy ----
        if (tid == 0) {
            while (atomicAdd(flag, 0) < 256) __builtin_amdgcn_s_sleep(8);
        }
        __syncthreads();
        float* wch = (float*)sm;              // [36][128]
        float* ech = (float*)(sm + 18432);    // [128][64]
        float* LG  = (float*)sm;              // [64][36] (aliases wch after barrier)
        int b = tid & 63;
        int wvU = __builtin_amdgcn_readfirstlane(tid >> 6);
        float accv[9];
#pragma unroll
        for (int it = 0; it < 9; ++it) accv[it] = 0.f;
        for (int ch = 0; ch < 8; ++ch) {
            __syncthreads();
            for (int e = tid; e < 36 * 128; e += 256)
                wch[e] = fc2_w[(e >> 7) * 1024 + ch * 128 + (e & 127)];
            for (int e = tid; e < 128 * 64; e += 256)
                ech[e] = e2T[(ch * 128 + (e >> 6)) * 64 + (e & 63)];
            __syncthreads();
            for (int jl = 0; jl < 128; ++jl) {
                float ev = ech[jl * 64 + b];
#pragma unroll
                for (int it = 0; it < 9; ++it)
                    accv[it] += ev * wch[(wvU + it * 4) * 128 + jl];
            }
        }
        __syncthreads();   // staging buffers dead; LG may alias them now
#pragma unroll
        for (int it = 0; it < 9; ++it) {
            int o = wvU + it * 4;
            LG[b * 36 + o] = accv[it] + fc2_b[o];
        }
        __syncthreads();
        if (tid < 64) {
            float loss = 0.f;
#pragma unroll
            for (int v = 0; v < 6; ++v) {
                float mx = -1e30f;
#pragma unroll
                for (int k = 0; k < 6; ++k) mx = fmaxf(mx, LG[tid * 36 + v * 6 + k]);
                float s = 0.f, ex[6];
#pragma unroll
                for (int k = 0; k < 6; ++k) { ex[k] = expf(LG[tid * 36 + v * 6 + k] - mx); s += ex[k]; }
                float inv = 1.f / s;
#pragma unroll
                for (int k = 0; k < 6; ++k) {
                    float dd = ex[k] * inv;
                    out[DIST_OFF + tid * 36 + v * 6 + k] = dd;
                    loss += dd * logf(dd + 1e-10f);
                }
            }
            out[LOSS_OFF + tid] = 0.1f * loss;
        }
        return;
    }

    // ---- decoder ----
    int wv = tid >> 6, lane = tid & 63, l15 = lane & 15, q = lane >> 4;
    int db = blockIdx.x - 257;
    int g0 = (db / 27) * 8, r0 = (db % 27) * 8;   // 2-D tile: 8 gh-rows x 8 r216-rows
    unsigned short* emL = (unsigned short*)sm;            // [64][160] bf16 = 20480
    unsigned short* h2L = (unsigned short*)(sm + 20480);  // [32 kb][64 m][8] = 32768
    float* sE2p = (float*)(sm + 20480);                   // aliases h2L (after barrier)
    float* sE2f = (float*)(sm + 21504);
    char* Ast = sm;   // GEMM1 A staging, 2x16KB dbuf (aliases emL + h2L head; dead before h2L)

    f32x4 acc[4][4];
#pragma unroll
    for (int a = 0; a < 4; ++a)
#pragma unroll
        for (int b = 0; b < 4; ++b) acc[a][b] = (f32x4){0.f, 0.f, 0.f, 0.f};

    // cooperative staged GEMM1: local row rho = lane (gh = g0 + rho/8, r216 = r0 + rho%8)
    int gh_t = g0 + (lane >> 3);
    int r_t  = r0 + (lane & 7);
    const unsigned short* shp = Sh  + gh_t * 1024 + wv * 32;
    const unsigned short* s3p = S3g + r_t  * 1024 + wv * 32;
    const unsigned short* bbase = W2 + (wv * 64 + l15) * 1024 + q * 8;
    int Xw = (lane & 7) << 4;   // write-side XOR swizzle
    int Xr = (l15 & 7) << 4;    // read-side XOR swizzle

    ushort8 rsh[4], rs3[4];
#pragma unroll
    for (int i = 0; i < 4; ++i) {
        rsh[i] = *(const ushort8*)(shp + i * 8);
        rs3[i] = *(const ushort8*)(s3p + i * 8);
    }
    short8 bpre[4];
#pragma unroll
    for (int j = 0; j < 4; ++j) bpre[j] = *(const short8*)(bbase + j * 16384);
#pragma unroll
    for (int i = 0; i < 4; ++i)
        *(short8*)(Ast + lane * 256 + ((wv * 64 + i * 16) ^ Xw)) = packrelu8(rsh[i], rs3[i]);
    BAR_LGKM();   // pack writes drained; B prefetch stays in flight

    for (int c = 0; c < 8; ++c) {
        int cb = (c & 1) << 14;
        if (c < 7) {   // issue next-chunk table loads early
            const unsigned short* p1 = shp + (c + 1) * 128;
            const unsigned short* p3 = s3p + (c + 1) * 128;
#pragma unroll
            for (int i = 0; i < 4; ++i) {
                rsh[i] = *(const ushort8*)(p1 + i * 8);
                rs3[i] = *(const ushort8*)(p3 + i * 8);
            }
        }
#pragma unroll
        for (int ss = 0; ss < 4; ++ss) {
            int s = c * 4 + ss;
            short8 af[4];
#pragma unroll
            for (int mt = 0; mt < 4; ++mt)
                af[mt] = *(const short8*)(Ast + cb + (mt * 16 + l15) * 256 + ((ss * 64 + q * 16) ^ Xr));
            short8 bcur[4];
#pragma unroll
            for (int j = 0; j < 4; ++j) bcur[j] = bpre[j];
            if (s < 31) {
#pragma unroll
                for (int j = 0; j < 4; ++j) bpre[j] = *(const short8*)(bbase + j * 16384 + (s + 1) * 32);
            }
#pragma unroll
            for (int mt = 0; mt < 4; ++mt)
#pragma unroll
                for (int j = 0; j < 4; ++j)
                    acc[mt][j] = __builtin_amdgcn_mfma_f32_16x16x32_bf16(af[mt], bcur[j], acc[mt][j], 0, 0, 0);
        }
        if (c < 7) {
            int nb = ((c + 1) & 1) << 14;
#pragma unroll
            for (int i = 0; i < 4; ++i)
                *(short8*)(Ast + nb + lane * 256 + ((wv * 64 + i * 16) ^ Xw)) = packrelu8(rsh[i], rs3[i]);
        }
        BAR_LGKM();   // LDS-drain only; in-flight bpre B-prefetch survives the barrier
    }

#pragma unroll
    for (int j = 0; j < 4; ++j) {
        int i = wv * 64 + j * 16 + l15;
        float cc = c2g[i];
#pragma unroll
        for (int mt = 0; mt < 4; ++mt)
#pragma unroll
            for (int r = 0; r < 4; ++r) {
                int m = mt * 16 + q * 4 + r;
                h2L[((i >> 3) * 64 + m) * 8 + (i & 7)] = f2bf(fmaxf(acc[mt][j][r] + cc, 0.f));
            }
    }
    __syncthreads();

    // ---- GEMM2 (operand-swapped: D[o = q*4+r][m = l15]) + in-register dct2 contraction ----
    float c3q[4], dwq0[4], dwq1[4], dwq2[4];
#pragma unroll
    for (int r = 0; r < 4; ++r) {
        int o = q * 4 + r;
        c3q[r]  = c3g[o];
        dwq0[r] = d2wg[o * 3 + 0];
        dwq1[r] = d2wg[o * 3 + 1];
        dwq2[r] = d2wg[o * 3 + 2];
    }
    float db0 = d2bg[0], db1 = d2bg[1], db2 = d2bg[2];
    float sE2acc[4] = {0.f, 0.f, 0.f, 0.f};

    for (int c = wv; c < 13; c += 4) {
        int hw0 = c * 4;
        f32x4 a2[4][4];
#pragma unroll
        for (int a = 0; a < 4; ++a)
#pragma unroll
            for (int b = 0; b < 4; ++b) a2[a][b] = (f32x4){0.f, 0.f, 0.f, 0.f};
        const unsigned short* b3[4];
#pragma unroll
        for (int j = 0; j < 4; ++j) {
            int hw = hw0 + j; if (hw > 48) hw = 48;
            b3[j] = W3 + (hw * 16 + l15) * 256 + q * 8;
        }
        short8 bpre2[4];
#pragma unroll
        for (int j = 0; j < 4; ++j) bpre2[j] = *(const short8*)(b3[j]);
#pragma unroll
        for (int s = 0; s < 8; ++s) {
            short8 bcur[4];
#pragma unroll
            for (int j = 0; j < 4; ++j) bcur[j] = bpre2[j];
            if (s < 7) {
#pragma unroll
                for (int j = 0; j < 4; ++j) bpre2[j] = *(const short8*)(b3[j] + (s + 1) * 32);
            }
            short8 af[4];
#pragma unroll
            for (int mt = 0; mt < 4; ++mt)
                af[mt] = *(const short8*)(h2L + ((s * 4 + q) * 64 + mt * 16 + l15) * 8);
            // swapped: A = W3 fragment (rows=o), B = H2 fragment (cols=m)
#pragma unroll
            for (int mt = 0; mt < 4; ++mt)
#pragma unroll
                for (int j = 0; j < 4; ++j)
                    a2[mt][j] = __builtin_amdgcn_mfma_f32_16x16x32_bf16(bcur[j], af[mt], a2[mt][j], 0, 0, 0);
        }
#pragma unroll
        for (int j = 0; j < 4; ++j) {
            int hw = hw0 + j;
            if (hw <= 48) {
#pragma unroll
                for (int mt = 0; mt < 4; ++mt) {
                    // lane holds h3[o=q*4+r][m=mt*16+l15], r=0..3
                    float p0 = 0.f, p1 = 0.f, p2 = 0.f;
#pragma unroll
                    for (int r = 0; r < 4; ++r) {
                        float h = fmaxf(a2[mt][j][r] + c3q[r], 0.f);
                        p0 += h * dwq0[r]; p1 += h * dwq1[r]; p2 += h * dwq2[r];
                    }
                    // reduce over q-groups (lanes ±16, ±32): all lanes get full sums
                    p0 += __shfl_xor(p0, 16); p0 += __shfl_xor(p0, 32);
                    p1 += __shfl_xor(p1, 16); p1 += __shfl_xor(p1, 32);
                    p2 += __shfl_xor(p2, 16); p2 += __shfl_xor(p2, 32);
                    unsigned short u0 = f2bf(p0 + db0), u1 = f2bf(p1 + db1), u2 = f2bf(p2 + db2);
                    float f0 = bf2f(u0), f1 = bf2f(u1), f2v = bf2f(u2);
                    if (q == 0) {
                        sE2acc[mt] += f0 * f0 + f1 * f1 + f2v * f2v;
                        unsigned short* er = emL + (mt * 16 + l15) * 160 + hw * 3;
                        er[0] = u0; er[1] = u1; er[2] = u2;
                    }
                }
            }
        }
    }
    __syncthreads();   // all h2L reads complete; sE2p/sE2f may alias it now
    if (q == 0) {
#pragma unroll
        for (int mt = 0; mt < 4; ++mt) sE2p[wv * 64 + mt * 16 + l15] = sE2acc[mt];
    }
    for (int e = tid; e < 64 * 13; e += 256) emL[(e / 13) * 160 + 147 + (e % 13)] = 0;
    __syncthreads();
    if (tid < 64) sE2f[tid] = sE2p[tid] + sE2p[64 + tid] + sE2p[128 + tid] + sE2p[192 + tid];
    __syncthreads();

    f32x4 aO[4];
#pragma unroll
    for (int j = 0; j < 4; ++j) aO[j] = (f32x4){0.f, 0.f, 0.f, 0.f};
    const unsigned short* xrow = Xg + (wv * 16 + l15) * 160 + q * 8;
#pragma unroll
    for (int s = 0; s < 5; ++s) {
        short8 af = *(const short8*)(xrow + s * 32);
#pragma unroll
        for (int j = 0; j < 4; ++j) {
            short8 bfv = *(const short8*)(emL + (j * 16 + l15) * 160 + s * 32 + q * 8);
            aO[j] = __builtin_amdgcn_mfma_f32_16x16x32_bf16(af, bfv, aO[j], 0, 0, 0);
        }
    }
    int b0 = wv * 16 + q * 4;
    float sxv[4];
#pragma unroll
    for (int r = 0; r < 4; ++r) sxv[r] = sx2g[b0 + r];
#pragma unroll
    for (int j = 0; j < 4; ++j) {
        int rloc = j * 16 + l15;
        int n = (g0 + (rloc >> 3)) * 216 + r0 + (rloc & 7);   // 2-D tile -> global code index
        float he = 0.5f * sE2f[rloc];
#pragma unroll
        for (int r = 0; r < 4; ++r)
            out[(size_t)(b0 + r) * NNC + n] = aO[j][r] - he - 0.5f * sxv[r];
    }
}

// ============================ launcher ============================

extern "C" void kernel_launch(void* const* d_in, const int* in_sizes, int n_in,
                              void* d_out, int out_size, void* d_ws, size_t ws_size,
                              hipStream_t stream) {
    const float* x       = (const float*)d_in[0];
    const float* conv_w  = (const float*)d_in[1];
    const float* conv_b  = (const float*)d_in[2];
    const float* ebn2_g  = (const float*)d_in[3];
    const float* ebn2_b  = (const float*)d_in[4];
    const float* fc1_w   = (const float*)d_in[5];
    const float* fc1_b   = (const float*)d_in[6];
    const float* ebn1_g  = (const float*)d_in[7];
    const float* ebn1_b  = (const float*)d_in[8];
    const float* fc2_w   = (const float*)d_in[9];
    const float* fc2_b   = (const float*)d_in[10];
    const float* embeds  = (const float*)d_in[11];
    const float* dfc1_w  = (const float*)d_in[12];
    const float* dfc1_b  = (const float*)d_in[13];
    const float* dbn1_g  = (const float*)d_in[14];
    const float* dbn1_b  = (const float*)d_in[15];
    const float* dbn1_rm = (const float*)d_in[16];
    const float* dbn1_rv = (const float*)d_in[17];
    const float* dfc2_w  = (const float*)d_in[18];
    const float* dfc2_b  = (const float*)d_in[19];
    const float* dbn2_g  = (const float*)d_in[20];
    const float* dbn2_b  = (const float*)d_in[21];
    const float* dbn2_rm = (const float*)d_in[22];
    const float* dbn2_rv = (const float*)d_in[23];
    const float* dct1_w  = (const float*)d_in[24];
    const float* dct1_b  = (const float*)d_in[25];
    const float* dbn3_g  = (const float*)d_in[26];
    const float* dbn3_b  = (const float*)d_in[27];
    const float* dbn3_rm = (const float*)d_in[28];
    const float* dbn3_rv = (const float*)d_in[29];
    const float* dct2_w  = (const float*)d_in[30];
    const float* dct2_b  = (const float*)d_in[31];

    float* ws  = (float*)d_ws;
    float* out = (float*)d_out;

    dvae_k1<<<401, 256, 0, stream>>>(x, conv_w, conv_b, ebn2_g, ebn2_b,
                                     embeds, dfc1_w, dfc1_b, dbn1_g, dbn1_b, dbn1_rm, dbn1_rv,
                                     dfc2_w, dfc2_b, dbn2_g, dbn2_b, dbn2_rm, dbn2_rv,
                                     dct1_w, dct1_b, dbn3_g, dbn3_b, dbn3_rm, dbn3_rv, ws);

    hipFuncSetAttribute(reinterpret_cast<const void*>(dvae_k3),
                        hipFuncAttributeMaxDynamicSharedMemorySize, LDS_BYTES);
    dvae_k3<<<986, 256, LDS_BYTES, stream>>>(
        (const unsigned short*)(ws + WS_SH), (const unsigned short*)(ws + WS_S3),
        (const unsigned short*)(ws + WS_W2BF), ws + WS_C2,
        (const unsigned short*)(ws + WS_W3BF), ws + WS_C3,
        dct2_w, dct2_b,
        (const unsigned short*)(ws + WS_XBF), ws + WS_SX2,
        fc1_w, fc1_b, ebn1_g, ebn1_b,
        ws + WS_E1T, ws + WS_E2T, (int*)(ws + WS_FLAG),
        fc2_w, fc2_b, out);
}